// Round 17
// baseline (121.794 us; speedup 1.0000x reference)
//
#include <hip/hip_runtime.h>
#include <math.h>

#define N_TOK 40
#define N1    41      // N_TOK + 1
#define BS    8
#define DD    256     // D
#define HH    256     // H
#define NTRI  10660   // C(41,3)
#define NPAIR 780     // pairs (i,k) with k-i>=2
#define ROWF  (BS * N1 * HH)  // 83968 floats per [b][t][h] array
#define MNEG  (-1e38f)
#define DPB   256
// score wave allocation (w-descending pair order -> closed-form segments):
//   p <  300 (nj>=16): 4 waves/pair  -> waves [0,1200)
//   p <  528 (nj>= 8): 2 waves/pair  -> waves [1200,1656)
//   p >= 528 (nj<  8): 1 wave /pair  -> waves [1656,1908)
#define WPB   1908            // waves per b
#define SBLK  (WPB * BS / 4)  // 3816 blocks of 4 waves

// ---------------- Kernel 1: projections, LDS-staged W1 slab (R13 verbatim, 9 µs)
__global__ __launch_bounds__(256) void k_proj(
    const float* __restrict__ enc, const float* __restrict__ W1,
    const float* __restrict__ b1v,
    float* __restrict__ P, float* __restrict__ Qb, float* __restrict__ Dd)
{
    const int blk  = blockIdx.x;       // 0..163
    const int t    = blk >> 2;         // 0..40
    const int hq   = blk & 3;          // h-quarter
    const int tid  = threadIdx.x;
    const int lane = tid & 63;
    const int pr   = tid >> 6;         // 0..3 (wave index = b-pair)

    __shared__ float w1T[512][64];     // 128 KB
    __shared__ float e[BS][DD];        // 8 KB

    #pragma unroll 8
    for (int r = pr; r < 512; r += 4)
        w1T[r][lane] = W1[(r << 8) + (hq << 6) + lane];
    for (int x = tid; x < BS * DD; x += 256)
        e[x >> 8][x & 255] = enc[(t * BS + (x >> 8)) * DD + (x & 255)];
    __syncthreads();

    const int h  = (hq << 6) + lane;
    const int bA = 2 * pr, bB = 2 * pr + 1;

    float a0 = 0.f, c0 = 0.f, a1 = 0.f, c1 = 0.f;
    #pragma unroll 8
    for (int d = 0; d < DD; ++d) {
        float wp = w1T[d][lane];
        float wq = w1T[256 + d][lane];
        float e0 = e[bA][d];
        float e1 = e[bB][d];
        a0 = fmaf(e0, wp, a0); c0 = fmaf(e0, wq, c0);
        a1 = fmaf(e1, wp, a1); c1 = fmaf(e1, wq, c1);
    }

    const float bb = b1v[h];
    const int iA = ((bA * N1) + t) * HH + h;
    const int iB = ((bB * N1) + t) * HH + h;
    P[iA]  = a0;          P[iB]  = a1;
    Qb[iA] = c0 + bb;     Qb[iB] = c1 + bb;
    Dd[iA] = a0 - c0;     Dd[iB] = a1 - c1;
}

// ---------------- Kernel 2: scores — PROPORTIONAL waves per pair.
// j-iterations are independent (each jp -> distinct S entry), so splitting
// a pair's jp range over nw waves is assignment-only: the per-triple
// 16-lane loads/fmaf/shfl/store are verbatim R12 -> S bitwise identical.
// Wave v of a pair covers jp ≡ 4v+js (mod 4*nw): heavy pairs (nj>=16)
// drop from 10 serial iterations to <=3.
__global__ __launch_bounds__(256) void k_score(
    const float* __restrict__ P, const float* __restrict__ Qb,
    const float* __restrict__ Dd, const float* __restrict__ W2,
    const float* __restrict__ b2, float* __restrict__ S)
{
    const int g    = blockIdx.x * 4 + (threadIdx.x >> 6);  // global wave
    const int lane = threadIdx.x & 63;
    const int js   = lane >> 4;      // j-slice within wave: 0..3
    const int t    = lane & 15;      // h-chunk

    const int u = g >> 3;            // wave-task within b (0..1907)
    const int b = g & 7;

    int p, v, nw;
    if (u < 1200)      { p = u >> 2;               v = u & 3;        nw = 4; }
    else if (u < 1656) { p = 300 + ((u - 1200) >> 1); v = (u - 1200) & 1; nw = 2; }
    else               { p = 528 + (u - 1656);     v = 0;            nw = 1; }

    int c = (int)((sqrtf(8.f * (float)p + 1.f) - 1.f) * 0.5f);
    while ((c + 1) * (c + 2) / 2 <= p) ++c;
    while (c * (c + 1) / 2 > p) --c;
    const int w    = 40 - c;
    const int i    = p - c * (c + 1) / 2;
    const int k    = i + w;
    const int nj   = w - 1;
    const int n2   = w - 2;
    const int base = n2 * (n2 + 1) * (119 - 2 * n2) / 6;   // == soff(w)

    const float4* Pr  = (const float4*)(P  + ((b * N1 + i) << 8)) + t * 4;
    const float4* Qr  = (const float4*)(Qb + ((b * N1 + k) << 8)) + t * 4;
    const float4* W2r = (const float4*)(W2) + t * 8;

    float4 pp[4], qq[4], wa[4], wb[4];
    #pragma unroll
    for (int q = 0; q < 4; ++q) {
        pp[q] = Pr[q]; qq[q] = Qr[q];
        wa[q] = W2r[q * 2]; wb[q] = W2r[q * 2 + 1];
    }
    const float bb0 = b2[0], bb1 = b2[1];
    float* Sout = S + b * NTRI + base + i * nj;

    const int step = 4 * nw;
    for (int jp = 4 * v + js; jp < nj; jp += step) {
        const float4* Drow =
            (const float4*)(Dd + ((b * N1 + i + 1 + jp) << 8)) + t * 4;
        float s0 = 0.f, s1 = 0.f;
        #pragma unroll
        for (int q = 0; q < 4; ++q) {
            float4 dd = Drow[q];
            float r0 = fmaxf(dd.x + qq[q].x - pp[q].x, 0.f);
            float r1 = fmaxf(dd.y + qq[q].y - pp[q].y, 0.f);
            float r2 = fmaxf(dd.z + qq[q].z - pp[q].z, 0.f);
            float r3 = fmaxf(dd.w + qq[q].w - pp[q].w, 0.f);
            s0 = fmaf(r0, wa[q].x, s0); s1 = fmaf(r0, wa[q].y, s1);
            s0 = fmaf(r1, wa[q].z, s0); s1 = fmaf(r1, wa[q].w, s1);
            s0 = fmaf(r2, wb[q].x, s0); s1 = fmaf(r2, wb[q].y, s1);
            s0 = fmaf(r3, wb[q].z, s0); s1 = fmaf(r3, wb[q].w, s1);
        }
        #pragma unroll
        for (int d = 1; d < 16; d <<= 1) {   // within 16-lane group
            s0 += __shfl_xor(s0, d);
            s1 += __shfl_xor(s1, d);
        }
        if (t == 0) {
            float S0 = s0 + bb0, S1 = s1 + bb1;
            Sout[jp] = fmaxf(S0, S1) + log1pf(__expf(-fabsf(S0 - S1)));
        }
    }
}

// ---------------- Kernel 3: per-batch DP, wave-synchronous (R16 verbatim)
__device__ __forceinline__ int tri_base(int i) { return (i * (81 - i)) >> 1; }
#define BIDX(i, j) (tri_base(i) + ((j) - (i) - 1))

constexpr int soff(int W) {
    int s = 0;
    for (int v = 2; v < W; ++v) s += (N1 - v) * (v - 1);
    return s;
}
constexpr int pick_TW(int m, int nj) {
    int T = 1;
    while (T < 64 && m * (T * 2) <= 64 && T < nj) T *= 2;
    return T;
}

template<int W>
__device__ __forceinline__ void dp_step_w(float* __restrict__ Btri,
                                          const float* __restrict__ Sl, int lane)
{
    constexpr int m    = N1 - W;
    constexpr int nj   = W - 1;
    constexpr int T    = pick_TW(m, nj);
    constexpr int CH   = (nj + T - 1) / T;
    constexpr int base = soff(W);

    if (lane < m * T) {
        const int i = lane / T;
        const int h = lane % T;
        const int k = i + W;

        float g[CH];
        #pragma unroll
        for (int q = 0; q < CH; ++q) {
            int jp = h + q * T;
            bool live = (q < CH - 1) || (jp < nj);
            int jj = live ? jp : 0;
            float v = Sl[base + i * nj + jj]
                    + Btri[BIDX(i, i + 1 + jj)]
                    + Btri[BIDX(i + 1 + jj, k)];
            g[q] = live ? v : MNEG;
        }
        float mx = g[0];
        #pragma unroll
        for (int q = 1; q < CH; ++q) mx = fmaxf(mx, g[q]);
        float s = 0.f;
        #pragma unroll
        for (int q = 0; q < CH; ++q) s += __expf(g[q] - mx);
        #pragma unroll
        for (int d = 1; d < T; d <<= 1) {
            float mo = __shfl_xor(mx, d);
            float so = __shfl_xor(s, d);
            float nm = fmaxf(mx, mo);
            s = s * __expf(mx - nm) + so * __expf(mo - nm);
            mx = nm;
        }
        if (h == 0)
            Btri[BIDX(i, k)] = mx + __logf(s);
    }
    // no barrier: single-wave execution
}

template<int W>
__device__ __forceinline__ void dp_from_w(float* __restrict__ Btri,
                                          const float* __restrict__ Sl, int lane)
{
    dp_step_w<W>(Btri, Sl, lane);
    if constexpr (W + 1 <= N_TOK) dp_from_w<W + 1>(Btri, Sl, lane);
}

__global__ __launch_bounds__(DPB) void k_dp(
    const float* __restrict__ Sg, const int* __restrict__ lengths,
    float* __restrict__ out)
{
    __shared__ __align__(16) float Sl[NTRI];
    __shared__ float Btri[820];
    const int tid = threadIdx.x;
    const int b   = blockIdx.x;

    const float4* src = (const float4*)(Sg + b * NTRI);
    float4* dst = (float4*)Sl;
    for (int x = tid; x < NTRI / 4; x += DPB) dst[x] = src[x];
    if (tid < N_TOK) Btri[tri_base(tid)] = 0.f;
    __syncthreads();   // the only barrier in the kernel

    if (tid < 64) {
        dp_from_w<2>(Btri, Sl, tid);
        if (tid == 0) {
            int L = lengths[b];
            out[b] = Btri[BIDX(0, L)];
        }
    }
}

extern "C" void kernel_launch(void* const* d_in, const int* in_sizes, int n_in,
                              void* d_out, int out_size, void* d_ws, size_t ws_size,
                              hipStream_t stream)
{
    const float* enc = (const float*)d_in[0];
    const float* W1  = (const float*)d_in[1];
    const float* b1  = (const float*)d_in[2];
    const float* W2  = (const float*)d_in[3];
    const float* b2  = (const float*)d_in[4];
    const int* lengths = (const int*)d_in[5];

    float* ws = (float*)d_ws;
    float* P  = ws;
    float* Qb = ws + ROWF;
    float* Dd = ws + 2 * ROWF;
    float* S  = ws + 3 * ROWF;

    k_proj<<<dim3(164), dim3(256), 0, stream>>>(enc, W1, b1, P, Qb, Dd);
    k_score<<<dim3(SBLK), dim3(256), 0, stream>>>(P, Qb, Dd, W2, b2, S);
    k_dp<<<dim3(BS), dim3(DPB), 0, stream>>>(S, lengths, (float*)d_out);
}

// Round 18
// 110.360 us; speedup vs baseline: 1.1036x; 1.1036x over previous
//
#include <hip/hip_runtime.h>
#include <math.h>

#define N_TOK 40
#define N1    41      // N_TOK + 1
#define BS    8
#define DD    256     // D
#define HH    256     // H
#define NTRI  10660   // C(41,3)
#define NPAIR 780     // pairs (i,k) with k-i>=2
#define NPTASK (NPAIR * BS)   // 6240 tasks, one WAVE each
#define ROWF  (BS * N1 * HH)  // 83968 floats per [b][t][h] array
#define MNEG  (-1e38f)
#define DPB   256

// ==================== R16 BEST-KNOWN CONFIGURATION (110.5 µs) ====================
// R17's proportional-wave score experiment regressed (+11.3 µs) and exposed
// the single-wave DP's context sensitivity; this is the verbatim revert to
// the measured optimum. Ledger: fill 40 | fixed ~13 | gaps ~26 | proj 9 |
// score 13.7 | dp ~10.7. All phase levers tested both directions (R8/R9/
// R13/R17 proj+score, R15/R16/R17 dp, R2/R6/R15 fusion) — this is the
// empirical minimum of the explored space.

// ---------------- Kernel 1: projections, LDS-staged W1 slab (R13 form, 9 µs)
__global__ __launch_bounds__(256) void k_proj(
    const float* __restrict__ enc, const float* __restrict__ W1,
    const float* __restrict__ b1v,
    float* __restrict__ P, float* __restrict__ Qb, float* __restrict__ Dd)
{
    const int blk  = blockIdx.x;       // 0..163
    const int t    = blk >> 2;         // 0..40
    const int hq   = blk & 3;          // h-quarter
    const int tid  = threadIdx.x;
    const int lane = tid & 63;
    const int pr   = tid >> 6;         // 0..3 (wave index = b-pair)

    __shared__ float w1T[512][64];     // 128 KB
    __shared__ float e[BS][DD];        // 8 KB

    #pragma unroll 8
    for (int r = pr; r < 512; r += 4)
        w1T[r][lane] = W1[(r << 8) + (hq << 6) + lane];
    for (int x = tid; x < BS * DD; x += 256)
        e[x >> 8][x & 255] = enc[(t * BS + (x >> 8)) * DD + (x & 255)];
    __syncthreads();

    const int h  = (hq << 6) + lane;
    const int bA = 2 * pr, bB = 2 * pr + 1;

    float a0 = 0.f, c0 = 0.f, a1 = 0.f, c1 = 0.f;
    #pragma unroll 8
    for (int d = 0; d < DD; ++d) {
        float wp = w1T[d][lane];
        float wq = w1T[256 + d][lane];
        float e0 = e[bA][d];
        float e1 = e[bB][d];
        a0 = fmaf(e0, wp, a0); c0 = fmaf(e0, wq, c0);
        a1 = fmaf(e1, wp, a1); c1 = fmaf(e1, wq, c1);
    }

    const float bb = b1v[h];
    const int iA = ((bA * N1) + t) * HH + h;
    const int iB = ((bB * N1) + t) * HH + h;
    P[iA]  = a0;          P[iB]  = a1;
    Qb[iA] = c0 + bb;     Qb[iB] = c1 + bb;
    Dd[iA] = a0 - c0;     Dd[iB] = a1 - c1;
}

// ---------------- Kernel 2: scores — one wave per (pair,b) task (R12 form, 13.7 µs)
__global__ __launch_bounds__(256) void k_score(
    const float* __restrict__ P, const float* __restrict__ Qb,
    const float* __restrict__ Dd, const float* __restrict__ W2,
    const float* __restrict__ b2, float* __restrict__ S)
{
    const int task = blockIdx.x * 4 + (threadIdx.x >> 6);  // one wave per task
    const int lane = threadIdx.x & 63;
    const int js   = lane >> 4;      // j-slice 0..3
    const int t    = lane & 15;      // h-chunk

    const int p = task >> 3;         // pair index, w descending
    const int b = task & 7;

    int c = (int)((sqrtf(8.f * (float)p + 1.f) - 1.f) * 0.5f);
    while ((c + 1) * (c + 2) / 2 <= p) ++c;
    while (c * (c + 1) / 2 > p) --c;
    const int w    = 40 - c;
    const int i    = p - c * (c + 1) / 2;
    const int k    = i + w;
    const int nj   = w - 1;
    const int n2   = w - 2;
    const int base = n2 * (n2 + 1) * (119 - 2 * n2) / 6;   // == soff(w)

    const float4* Pr  = (const float4*)(P  + ((b * N1 + i) << 8)) + t * 4;
    const float4* Qr  = (const float4*)(Qb + ((b * N1 + k) << 8)) + t * 4;
    const float4* W2r = (const float4*)(W2) + t * 8;

    float4 pp[4], qq[4], wa[4], wb[4];
    #pragma unroll
    for (int q = 0; q < 4; ++q) {
        pp[q] = Pr[q]; qq[q] = Qr[q];
        wa[q] = W2r[q * 2]; wb[q] = W2r[q * 2 + 1];
    }
    const float bb0 = b2[0], bb1 = b2[1];
    float* Sout = S + b * NTRI + base + i * nj;

    for (int jp = js; jp < nj; jp += 4) {
        const float4* Drow =
            (const float4*)(Dd + ((b * N1 + i + 1 + jp) << 8)) + t * 4;
        float s0 = 0.f, s1 = 0.f;
        #pragma unroll
        for (int q = 0; q < 4; ++q) {
            float4 dd = Drow[q];
            float r0 = fmaxf(dd.x + qq[q].x - pp[q].x, 0.f);
            float r1 = fmaxf(dd.y + qq[q].y - pp[q].y, 0.f);
            float r2 = fmaxf(dd.z + qq[q].z - pp[q].z, 0.f);
            float r3 = fmaxf(dd.w + qq[q].w - pp[q].w, 0.f);
            s0 = fmaf(r0, wa[q].x, s0); s1 = fmaf(r0, wa[q].y, s1);
            s0 = fmaf(r1, wa[q].z, s0); s1 = fmaf(r1, wa[q].w, s1);
            s0 = fmaf(r2, wb[q].x, s0); s1 = fmaf(r2, wb[q].y, s1);
            s0 = fmaf(r3, wb[q].z, s0); s1 = fmaf(r3, wb[q].w, s1);
        }
        #pragma unroll
        for (int d = 1; d < 16; d <<= 1) {   // within 16-lane group
            s0 += __shfl_xor(s0, d);
            s1 += __shfl_xor(s1, d);
        }
        if (t == 0) {
            float S0 = s0 + bb0, S1 = s1 + bb1;
            Sout[jp] = fmaxf(S0, S1) + log1pf(__expf(-fabsf(S0 - S1)));
        }
    }
}

// ---------------- Kernel 3: per-batch DP, wave-synchronous (R16 form, ~10.7 µs)
__device__ __forceinline__ int tri_base(int i) { return (i * (81 - i)) >> 1; }
#define BIDX(i, j) (tri_base(i) + ((j) - (i) - 1))

constexpr int soff(int W) {
    int s = 0;
    for (int v = 2; v < W; ++v) s += (N1 - v) * (v - 1);
    return s;
}
constexpr int pick_TW(int m, int nj) {
    int T = 1;
    while (T < 64 && m * (T * 2) <= 64 && T < nj) T *= 2;
    return T;
}

template<int W>
__device__ __forceinline__ void dp_step_w(float* __restrict__ Btri,
                                          const float* __restrict__ Sl, int lane)
{
    constexpr int m    = N1 - W;
    constexpr int nj   = W - 1;
    constexpr int T    = pick_TW(m, nj);
    constexpr int CH   = (nj + T - 1) / T;
    constexpr int base = soff(W);

    if (lane < m * T) {
        const int i = lane / T;
        const int h = lane % T;
        const int k = i + W;

        float g[CH];
        #pragma unroll
        for (int q = 0; q < CH; ++q) {
            int jp = h + q * T;
            bool live = (q < CH - 1) || (jp < nj);
            int jj = live ? jp : 0;
            float v = Sl[base + i * nj + jj]
                    + Btri[BIDX(i, i + 1 + jj)]
                    + Btri[BIDX(i + 1 + jj, k)];
            g[q] = live ? v : MNEG;
        }
        float mx = g[0];
        #pragma unroll
        for (int q = 1; q < CH; ++q) mx = fmaxf(mx, g[q]);
        float s = 0.f;
        #pragma unroll
        for (int q = 0; q < CH; ++q) s += __expf(g[q] - mx);
        #pragma unroll
        for (int d = 1; d < T; d <<= 1) {
            float mo = __shfl_xor(mx, d);
            float so = __shfl_xor(s, d);
            float nm = fmaxf(mx, mo);
            s = s * __expf(mx - nm) + so * __expf(mo - nm);
            mx = nm;
        }
        if (h == 0)
            Btri[BIDX(i, k)] = mx + __logf(s);
    }
    // no barrier: single-wave execution, in-wave LDS ordering via waitcnt
}

template<int W>
__device__ __forceinline__ void dp_from_w(float* __restrict__ Btri,
                                          const float* __restrict__ Sl, int lane)
{
    dp_step_w<W>(Btri, Sl, lane);
    if constexpr (W + 1 <= N_TOK) dp_from_w<W + 1>(Btri, Sl, lane);
}

__global__ __launch_bounds__(DPB) void k_dp(
    const float* __restrict__ Sg, const int* __restrict__ lengths,
    float* __restrict__ out)
{
    __shared__ __align__(16) float Sl[NTRI];
    __shared__ float Btri[820];
    const int tid = threadIdx.x;
    const int b   = blockIdx.x;

    const float4* src = (const float4*)(Sg + b * NTRI);
    float4* dst = (float4*)Sl;
    for (int x = tid; x < NTRI / 4; x += DPB) dst[x] = src[x];
    if (tid < N_TOK) Btri[tri_base(tid)] = 0.f;
    __syncthreads();   // the only barrier in the kernel

    if (tid < 64) {
        dp_from_w<2>(Btri, Sl, tid);
        if (tid == 0) {
            int L = lengths[b];
            out[b] = Btri[BIDX(0, L)];
        }
    }
}

extern "C" void kernel_launch(void* const* d_in, const int* in_sizes, int n_in,
                              void* d_out, int out_size, void* d_ws, size_t ws_size,
                              hipStream_t stream)
{
    const float* enc = (const float*)d_in[0];
    const float* W1  = (const float*)d_in[1];
    const float* b1  = (const float*)d_in[2];
    const float* W2  = (const float*)d_in[3];
    const float* b2  = (const float*)d_in[4];
    const int* lengths = (const int*)d_in[5];

    float* ws = (float*)d_ws;
    float* P  = ws;
    float* Qb = ws + ROWF;
    float* Dd = ws + 2 * ROWF;
    float* S  = ws + 3 * ROWF;

    k_proj<<<dim3(164), dim3(256), 0, stream>>>(enc, W1, b1, P, Qb, Dd);
    k_score<<<dim3(NPTASK / 4), dim3(256), 0, stream>>>(P, Qb, Dd, W2, b2, S);
    k_dp<<<dim3(BS), dim3(DPB), 0, stream>>>(S, lengths, (float*)d_out);
}